// Round 9
// baseline (5144.951 us; speedup 1.0000x reference)
//
#include <hip/hip_runtime.h>
#include <hip/hip_bf16.h>

#define NLAYERS 6
#define BB 8
#define TT 512
#define DMODEL 2048
#define DSTATE 128
#define DCONV 4
#define DINNER 4096
#define NTOK (BB*TT)              // 4096 tokens

typedef __bf16 bf16x8 __attribute__((ext_vector_type(8)));
typedef float floatx4 __attribute__((ext_vector_type(4)));
typedef unsigned short ushort8v __attribute__((ext_vector_type(8)));
typedef unsigned short ushort4v __attribute__((ext_vector_type(4)));

__device__ __forceinline__ float bf2f(unsigned short u) {
    return __uint_as_float(((unsigned)u) << 16);
}
__device__ __forceinline__ unsigned short f2bf(float f) {
    unsigned u = __float_as_uint(f);
    unsigned r = u + 0x7FFFu + ((u >> 16) & 1u);   // round-nearest-even
    return (unsigned short)(r >> 16);
}
__device__ __forceinline__ float siluf(float x) { return x / (1.f + __expf(-x)); }
__device__ __forceinline__ float softplusf(float x) {
    return fmaxf(x, 0.f) + log1pf(__expf(-fabsf(x)));
}

__device__ __forceinline__ void gload16(const void* g, void* l) {
    __builtin_amdgcn_global_load_lds(
        (const __attribute__((address_space(1))) void*)g,
        (__attribute__((address_space(3))) void*)l, 16, 0, 0);
}

// ---------------- fp32 -> bf16 weight conversion ----------------
__global__ __launch_bounds__(256) void cvt_kernel(const float* __restrict__ s,
                                                  unsigned short* __restrict__ d, int n) {
    int i = (blockIdx.x * blockDim.x + threadIdx.x) * 4;
    if (i < n) {
        float4 v = *(const float4*)(s + i);
        ushort4v o = {f2bf(v.x), f2bf(v.y), f2bf(v.z), f2bf(v.w)};
        *(ushort4v*)(d + i) = o;
    }
}

// ---------------- LayerNorm: fp32 in -> bf16 out ----------------
__global__ __launch_bounds__(256) void ln_kernel(const float* __restrict__ x,
                                                 const float* __restrict__ g,
                                                 const float* __restrict__ b,
                                                 unsigned short* __restrict__ out) {
    const int row = blockIdx.x;
    const float* xr = x + (long)row * DMODEL;
    const int base = threadIdx.x * 8;
    float4 v0 = *(const float4*)(xr + base);
    float4 v1 = *(const float4*)(xr + base + 4);
    float vv[8] = {v0.x, v0.y, v0.z, v0.w, v1.x, v1.y, v1.z, v1.w};
    float s = 0.f, s2 = 0.f;
#pragma unroll
    for (int j = 0; j < 8; j++) { s += vv[j]; s2 += vv[j] * vv[j]; }
#pragma unroll
    for (int off = 32; off >= 1; off >>= 1) {
        s += __shfl_xor(s, off);
        s2 += __shfl_xor(s2, off);
    }
    __shared__ float red[8];
    int wave = threadIdx.x >> 6, lane = threadIdx.x & 63;
    if (lane == 0) { red[wave] = s; red[4 + wave] = s2; }
    __syncthreads();
    s = red[0] + red[1] + red[2] + red[3];
    s2 = red[4] + red[5] + red[6] + red[7];
    float mu = s * (1.f / DMODEL);
    float var = s2 * (1.f / DMODEL) - mu * mu;
    float rs = rsqrtf(var + 1e-5f);
    ushort8v ov;
#pragma unroll
    for (int j = 0; j < 8; j++)
        ov[j] = f2bf((vv[j] - mu) * rs * g[base + j] + b[base + j]);
    *(ushort8v*)&out[(long)row * DMODEL + base] = ov;
}

// ---------------- combine: hout = p0 + p1 + h ----------------
__global__ __launch_bounds__(256) void combine3_kernel(const float* __restrict__ p0,
                                                       const float* __restrict__ p1,
                                                       const float* __restrict__ h,
                                                       float* __restrict__ out) {
    long i = (long)(blockIdx.x * blockDim.x + threadIdx.x) * 4;
    float4 a = *(const float4*)(p0 + i);
    float4 b = *(const float4*)(p1 + i);
    float4 c = *(const float4*)(h + i);
    float4 o = {a.x+b.x+c.x, a.y+b.y+c.y, a.z+b.z+c.z, a.w+b.w+c.w};
    *(float4*)(out + i) = o;
}

// ---------------- bc = sum of 4 K-split partials ----------------
__global__ __launch_bounds__(256) void bcsum_kernel(const float* __restrict__ bcp,
                                                    float* __restrict__ bc) {
    long i = (long)(blockIdx.x * blockDim.x + threadIdx.x) * 4;
    const long S = (long)NTOK * 256;
    float4 a = *(const float4*)(bcp + i);
    float4 b = *(const float4*)(bcp + S + i);
    float4 c = *(const float4*)(bcp + 2*S + i);
    float4 d = *(const float4*)(bcp + 3*S + i);
    float4 o = {a.x+b.x+c.x+d.x, a.y+b.y+c.y+d.y, a.z+b.z+c.z+d.z, a.w+b.w+c.w+d.w};
    *(float4*)(bc + i) = o;
}

// ============ m97-structure 128x128 GEMM: C = A[M,K]*B[N,K]^T ============
// 256 thr (4 waves: wm=w>>1, wn=w&1; wave tile 64x64, acc[4][4] 16x16 frags).
// BK=32, double-buffered LDS 2 x (A 8KB + B 8KB) = 32KB -> 4 blocks/CU target
// (__launch_bounds__(256,4)); inter-block overlap absorbs the barrier drain (m114).
// One __syncthreads() per K-tile (compiler emits the vmcnt/lgkm drain).
// LDS layout: 2 matrix rows per 128B LDS row, 8x16B slots; stored slot =
// ((r&1)*4 + chunk) ^ ((r>>1)&7) -- the R3-verified 0-conflict XOR swizzle,
// applied on the pre-swizzled global source (write) and lane-const read addr.
// Swapped-operand MFMA: mfma(B,A) -> M-row = lane&15, N-col = (lane>>4)*4+reg
// (4 consecutive cols/reg -> vectorized stores). EPI: 0 = bf16 store (W_in);
// 1 = softplus dmean atomics (W_dt); 2 = bcp K-part (W_xp); 3 = fp32 K-part (W_out).

template <int EPI>
__global__ __launch_bounds__(256, 4) void gemm128(const unsigned short* __restrict__ A,
                                                  const unsigned short* __restrict__ B,
                                                  int Kstr, int KT, int ldc,
                                                  unsigned short* __restrict__ obf,
                                                  float* __restrict__ of0,
                                                  float* __restrict__ of1,
                                                  const float* __restrict__ bias,
                                                  float* __restrict__ dmean) {
    __shared__ __align__(16) char lds[32768];
    const int tid = threadIdx.x;
    const int w = tid >> 6, lane = tid & 63;
    const int wm = w >> 1, wn = w & 1;
    const int lrow = lane & 15;

    // per-XCD clustering: block -> XCD b&7; RY=4 rows per XCD, column-major walk
    const int xcd = blockIdx.x & 7;
    const int l = blockIdx.x >> 3;
    const int by = xcd * 4 + (l & 3);
    const int rest = l >> 2;
    int bx = 0, kpart = 0;
    if constexpr (EPI == 0 || EPI == 1) { bx = rest; }
    else if constexpr (EPI == 2) { bx = rest & 1; kpart = rest >> 1; }
    else { bx = rest & 15; kpart = rest >> 4; }
    const long rowBase = (long)by * 128;
    const long colBase = (long)bx * 128;
    const long K0b = (long)kpart * KT * 64;     // byte offset into K

    // staging maps: thread tid writes LDS bytes [u*4096 + tid*16]; inverse-swizzled source
    const int t8 = tid >> 3;
    const int ch3 = (tid & 7) ^ (t8 & 7);
    const int rloc = 2 * t8 + (ch3 >> 2);
    const int coff = (ch3 & 3) * 16;
    const size_t Kb2 = (size_t)Kstr * 2;
    const char* pA0 = (const char*)A + (rowBase + rloc) * Kb2 + coff + K0b;
    const char* pA1 = (const char*)A + (rowBase + 64 + rloc) * Kb2 + coff + K0b;
    const char* pB0 = (const char*)B + (colBase + rloc) * Kb2 + coff + K0b;
    const char* pB1 = (const char*)B + (colBase + 64 + rloc) * Kb2 + coff + K0b;
    char* dA0 = lds + w * 1024;
    char* dA1 = lds + 4096 + w * 1024;
    char* dB0 = lds + 8192 + w * 1024;
    char* dB1 = lds + 12288 + w * 1024;

    // frag-read lane constants (slot = ((lane&1)*4 | lane>>4) ^ ((lane>>1)&7))
    const int slotRD = (((((lane & 1) << 2) | (lane >> 4)) ^ ((lane >> 1) & 7))) * 16;
    const int rbA = wm * 4096 + ((lane >> 1) & 7) * 128 + slotRD;
    const int rbB = 8192 + wn * 4096 + ((lane >> 1) & 7) * 128 + slotRD;

    floatx4 acc[4][4];
#pragma unroll
    for (int m = 0; m < 4; m++)
#pragma unroll
        for (int n = 0; n < 4; n++) acc[m][n] = floatx4{0.f, 0.f, 0.f, 0.f};
    bf16x8 af[4], bfr[4];

#define STAGE(BO, TOFF) do { \
    gload16(pA0 + (TOFF), dA0 + (BO)); \
    gload16(pA1 + (TOFF), dA1 + (BO)); \
    gload16(pB0 + (TOFF), dB0 + (BO)); \
    gload16(pB1 + (TOFF), dB1 + (BO)); } while (0)

    STAGE(0, 0);
    __syncthreads();

    for (int t = 0; t < KT; t++) {
        const int bo = (t & 1) * 16384;
        if (t + 1 < KT) STAGE(16384 - bo, (size_t)(t + 1) * 64);
#pragma unroll
        for (int m = 0; m < 4; m++)
            af[m] = *(const bf16x8*)(lds + bo + rbA + m * 1024);
#pragma unroll
        for (int n = 0; n < 4; n++)
            bfr[n] = *(const bf16x8*)(lds + bo + rbB + n * 1024);
#pragma unroll
        for (int m = 0; m < 4; m++)
#pragma unroll
            for (int n = 0; n < 4; n++)
                acc[m][n] = __builtin_amdgcn_mfma_f32_16x16x32_bf16(bfr[n], af[m], acc[m][n], 0, 0, 0);
        __syncthreads();   // drains staged t+1; all waves done reading buf
    }
#undef STAGE

    // ---------------- epilogue (M-row = lane&15, N-col = (lane>>4)*4 + reg) ----------------
    const int cg = (lane >> 4) * 4;
    if constexpr (EPI == 0) {
#pragma unroll
        for (int mi = 0; mi < 4; mi++)
#pragma unroll
            for (int n = 0; n < 4; n++) {
                long row = rowBase + wm * 64 + mi * 16 + lrow;
                long col = colBase + wn * 64 + n * 16 + cg;
                ushort4v o = {f2bf(acc[mi][n][0]), f2bf(acc[mi][n][1]),
                              f2bf(acc[mi][n][2]), f2bf(acc[mi][n][3])};
                *(ushort4v*)&obf[row * ldc + col] = o;
            }
    } else if constexpr (EPI == 1) {
        // delta: softplus(acc + b_dt) summed over cols -> dmean atomics
        float4 bi[4];
#pragma unroll
        for (int n = 0; n < 4; n++)
            bi[n] = *(const float4*)&bias[colBase + wn * 64 + n * 16 + cg];
#pragma unroll
        for (int mi = 0; mi < 4; mi++) {
            float s = 0.f;
#pragma unroll
            for (int n = 0; n < 4; n++) {
                s += softplusf(acc[mi][n][0] + bi[n].x);
                s += softplusf(acc[mi][n][1] + bi[n].y);
                s += softplusf(acc[mi][n][2] + bi[n].z);
                s += softplusf(acc[mi][n][3] + bi[n].w);
            }
            s += __shfl_xor(s, 16);
            s += __shfl_xor(s, 32);
            if ((lane >> 4) == 0)
                atomicAdd(&dmean[rowBase + wm * 64 + mi * 16 + lrow], s);
        }
    } else if constexpr (EPI == 2) {
        // W_xp K-split partial -> bcp[kpart][row][256]
        float* op = of0 + (long)kpart * NTOK * 256;
#pragma unroll
        for (int mi = 0; mi < 4; mi++)
#pragma unroll
            for (int n = 0; n < 4; n++) {
                long row = rowBase + wm * 64 + mi * 16 + lrow;
                long col = colBase + wn * 64 + n * 16 + cg;
                floatx4 o = acc[mi][n];
                *(floatx4*)&op[row * 256 + col] = o;
            }
    } else {
        // W_out K-split partial -> p0/p1
        float* op = (kpart == 0) ? of0 : of1;
#pragma unroll
        for (int mi = 0; mi < 4; mi++)
#pragma unroll
            for (int n = 0; n < 4; n++) {
                long row = rowBase + wm * 64 + mi * 16 + lrow;
                long col = colBase + wn * 64 + n * 16 + cg;
                floatx4 o = acc[mi][n];
                *(floatx4*)&op[row * ldc + col] = o;
            }
    }
}

// ---------------- causal depthwise conv1d + bias + silu ----------------
__global__ __launch_bounds__(256) void conv_silu_kernel(const unsigned short* __restrict__ xr,
                                                        const float* __restrict__ w,
                                                        const float* __restrict__ cb,
                                                        unsigned short* __restrict__ xc) {
    int idx = blockIdx.x * blockDim.x + threadIdx.x;   // NTOK * 512
    int d0 = (idx & 511) * 8;
    int bt = idx >> 9;
    int t = bt & (TT - 1);
    float acc[8];
#pragma unroll
    for (int j = 0; j < 8; j++) acc[j] = cb[d0 + j];
#pragma unroll
    for (int k = 0; k < DCONV; k++) {
        int ts = t - (DCONV - 1) + k;
        if (ts < 0) continue;
        ushort8v v = *(const ushort8v*)&xr[(long)(bt - (DCONV - 1) + k) * (2 * DINNER) + d0];
#pragma unroll
        for (int j = 0; j < 8; j++) acc[j] += bf2f(v[j]) * w[(d0 + j) * DCONV + k];
    }
    ushort8v ov;
#pragma unroll
    for (int j = 0; j < 8; j++) ov[j] = f2bf(siluf(acc[j]));
    *(ushort8v*)&xc[(long)bt * DINNER + d0] = ov;
}

// ---------------- sequential selective-scan (1 wave per batch) ----------------
__global__ void scan_kernel(const float* __restrict__ dmean, const float* __restrict__ bcmat,
                            const float* __restrict__ A_log, float* __restrict__ ys) {
    int b = blockIdx.x, lane = threadIdx.x;   // 64 lanes, 2 states each
    float A0 = -expf(A_log[lane]);
    float A1 = -expf(A_log[lane + 64]);
    float h0 = 0.f, h1 = 0.f;
    const float inv = 1.f / (float)DINNER;
    const float* rowp = bcmat + (long)b * TT * (2 * DSTATE);
    const float* dmp = dmean + b * TT;
    float B0 = rowp[lane], B1 = rowp[64 + lane];
    float C0 = rowp[128 + lane], C1 = rowp[192 + lane];
    float DM = dmp[0];
    for (int t = 0; t < TT; t++) {
        float nB0 = 0.f, nB1 = 0.f, nC0 = 0.f, nC1 = 0.f, nDM = 0.f;
        if (t + 1 < TT) {
            const float* nx = rowp + (long)(t + 1) * 256;
            nB0 = nx[lane]; nB1 = nx[64 + lane];
            nC0 = nx[128 + lane]; nC1 = nx[192 + lane];
            nDM = dmp[t + 1];
        }
        float dm = DM * inv;
        h0 = h0 * __expf(dm * A0) + B0;
        h1 = h1 * __expf(dm * A1) + B1;
        float v = h0 * C0 + h1 * C1;
#pragma unroll
        for (int off = 32; off >= 1; off >>= 1) v += __shfl_xor(v, off);
        if (lane == 0) ys[b * TT + t] = v;
        B0 = nB0; B1 = nB1; C0 = nC0; C1 = nC1; DM = nDM;
    }
}

// ---------------- y = (ys + D_skip*xc) * silu(res) ----------------
__global__ __launch_bounds__(256) void ycomb_kernel(const float* __restrict__ ys,
                                                    const unsigned short* __restrict__ xc,
                                                    const unsigned short* __restrict__ xr,
                                                    const float* __restrict__ dskip,
                                                    unsigned short* __restrict__ yc) {
    int idx = blockIdx.x * blockDim.x + threadIdx.x;
    int d0 = (idx & 511) * 8;
    int bt = idx >> 9;
    float y = ys[bt];
    ushort8v xcv = *(const ushort8v*)&xc[(long)bt * DINNER + d0];
    ushort8v rv = *(const ushort8v*)&xr[(long)bt * (2 * DINNER) + DINNER + d0];
    ushort8v ov;
#pragma unroll
    for (int j = 0; j < 8; j++) {
        float val = (y + dskip[d0 + j] * bf2f(xcv[j])) * siluf(bf2f(rv[j]));
        ov[j] = f2bf(val);
    }
    *(ushort8v*)&yc[(long)bt * DINNER + d0] = ov;
}

extern "C" void kernel_launch(void* const* d_in, const int* in_sizes, int n_in,
                              void* d_out, int out_size, void* d_ws, size_t ws_size,
                              hipStream_t stream) {
    const float* x      = (const float*)d_in[0];
    const float* ln_g   = (const float*)d_in[1];
    const float* ln_b   = (const float*)d_in[2];
    const float* W_in   = (const float*)d_in[3];
    const float* conv_w = (const float*)d_in[4];
    const float* conv_b = (const float*)d_in[5];
    const float* W_xp   = (const float*)d_in[6];
    const float* W_dt   = (const float*)d_in[7];
    const float* b_dt   = (const float*)d_in[8];
    const float* A_log  = (const float*)d_in[9];
    const float* D_skip = (const float*)d_in[10];
    const float* W_out  = (const float*)d_in[11];
    float* out = (float*)d_out;

    // workspace carve
    char* ws = (char*)d_ws;
    const size_t nWin  = (size_t)2 * DINNER * DMODEL;
    const size_t nWdt  = (size_t)DINNER * DINNER;
    const size_t nWxp  = (size_t)2 * DSTATE * DINNER;
    const size_t nWout = (size_t)DMODEL * DINNER;

    unsigned short* wb_in  = (unsigned short*)ws; ws += nWin * 2;
    unsigned short* wb_dt  = (unsigned short*)ws; ws += nWdt * 2;
    unsigned short* wb_xp  = (unsigned short*)ws; ws += nWxp * 2;
    unsigned short* wb_out = (unsigned short*)ws; ws += nWout * 2;
    unsigned short* xn = (unsigned short*)ws; ws += (size_t)NTOK * DMODEL * 2;
    unsigned short* xr = (unsigned short*)ws; ws += (size_t)NTOK * 2 * DINNER * 2;
    unsigned short* xc = (unsigned short*)ws; ws += (size_t)NTOK * DINNER * 2;
    unsigned short* yc = (unsigned short*)ws; ws += (size_t)NTOK * DINNER * 2;
    float* bc    = (float*)ws; ws += (size_t)NTOK * 2 * DSTATE * 4;
    float* bcp   = (float*)ws; ws += (size_t)4 * NTOK * 2 * DSTATE * 4;
    float* dmean = (float*)ws; ws += (size_t)NTOK * 4;
    float* ysb   = (float*)ws; ws += (size_t)NTOK * 4;
    float* h0    = (float*)ws; ws += (size_t)NTOK * DMODEL * 4;
    float* h1    = (float*)ws; ws += (size_t)NTOK * DMODEL * 4;
    float* p0    = (float*)ws; ws += (size_t)NTOK * DMODEL * 4;
    float* p1    = (float*)ws; ws += (size_t)NTOK * DMODEL * 4;

    const float* hprev = x;
    for (int lay = 0; lay < NLAYERS; lay++) {
        cvt_kernel<<<(int)(nWin / 1024), 256, 0, stream>>>(W_in + (size_t)lay * nWin, wb_in, (int)nWin);
        cvt_kernel<<<(int)(nWdt / 1024), 256, 0, stream>>>(W_dt + (size_t)lay * nWdt, wb_dt, (int)nWdt);
        cvt_kernel<<<(int)(nWxp / 1024), 256, 0, stream>>>(W_xp + (size_t)lay * nWxp, wb_xp, (int)nWxp);
        cvt_kernel<<<(int)(nWout / 1024), 256, 0, stream>>>(W_out + (size_t)lay * nWout, wb_out, (int)nWout);

        hipMemsetAsync(dmean, 0, (size_t)NTOK * 4, stream);

        // 1) LayerNorm
        ln_kernel<<<NTOK, 256, 0, stream>>>(hprev, ln_g + lay * DMODEL, ln_b + lay * DMODEL, xn);

        // 2) x_and_res = xn @ W_in^T  [4096 x 8192], K=2048: grid 32y x 64x = 2048 (= 2x1024 exact)
        gemm128<0><<<2048, 256, 0, stream>>>(xn, wb_in, DMODEL, 64, 2 * DINNER,
                                             xr, nullptr, nullptr, nullptr, nullptr);

        // 3) causal depthwise conv + silu
        conv_silu_kernel<<<NTOK * 512 / 256, 256, 0, stream>>>(
            xr, conv_w + (size_t)lay * DINNER * DCONV, conv_b + (size_t)lay * DINNER, xc);

        // 4a) W_dt [4096 x 4096], K=4096 full: grid 32y x 32x = 1024 (exact), delta epilogue
        gemm128<1><<<1024, 256, 0, stream>>>(xc, wb_dt, DINNER, 128, 0,
                                             nullptr, nullptr, nullptr,
                                             b_dt + (size_t)lay * DINNER, dmean);

        // 4b) W_xp [4096 x 256], K-split x4 (KT=32): grid 32y x 2x x 4k = 256
        gemm128<2><<<256, 256, 0, stream>>>(xc, wb_xp, DINNER, 32, 0,
                                            nullptr, bcp, nullptr, nullptr, nullptr);

        // 4c) bc = sum of partials
        bcsum_kernel<<<(NTOK * 256 / 4) / 256, 256, 0, stream>>>(bcp, bc);

        // 5) sequential scan -> ys
        scan_kernel<<<BB, 64, 0, stream>>>(dmean, bc, A_log + (size_t)lay * DSTATE, ysb);

        // 6) y = (ys + D_skip*xc) * silu(res)
        ycomb_kernel<<<NTOK * 512 / 256, 256, 0, stream>>>(
            ysb, xc, xr, D_skip + (size_t)lay * DINNER, yc);

        // 7) W_out partials [4096 x 2048], K-split x2 (KT=64): grid 32y x 16x x 2k = 1024 (exact)
        gemm128<3><<<1024, 256, 0, stream>>>(yc, wb_out, DINNER, 64, DMODEL,
                                             nullptr, p0, p1, nullptr, nullptr);

        // 8) hout = p0 + p1 + hprev  (residual); last layer writes d_out
        float* hcur = (lay == NLAYERS - 1) ? out : ((lay & 1) ? h1 : h0);
        combine3_kernel<<<(NTOK * DMODEL / 4) / 256, 256, 0, stream>>>(p0, p1, hprev, hcur);
        hprev = hcur;
    }
    (void)in_sizes; (void)n_in; (void)out_size; (void)ws_size;
}

// Round 10
// 4461.989 us; speedup vs baseline: 1.1531x; 1.1531x over previous
//
#include <hip/hip_runtime.h>
#include <hip/hip_bf16.h>

#define NLAYERS 6
#define BB 8
#define TT 512
#define DMODEL 2048
#define DSTATE 128
#define DCONV 4
#define DINNER 4096
#define NTOK (BB*TT)              // 4096 tokens

typedef __bf16 bf16x8 __attribute__((ext_vector_type(8)));
typedef float floatx4 __attribute__((ext_vector_type(4)));
typedef unsigned short ushort8v __attribute__((ext_vector_type(8)));
typedef unsigned short ushort4v __attribute__((ext_vector_type(4)));

__device__ __forceinline__ float bf2f(unsigned short u) {
    return __uint_as_float(((unsigned)u) << 16);
}
__device__ __forceinline__ unsigned short f2bf(float f) {
    unsigned u = __float_as_uint(f);
    unsigned r = u + 0x7FFFu + ((u >> 16) & 1u);   // round-nearest-even
    return (unsigned short)(r >> 16);
}
__device__ __forceinline__ float siluf(float x) { return x / (1.f + __expf(-x)); }
__device__ __forceinline__ float softplusf(float x) {
    return fmaxf(x, 0.f) + log1pf(__expf(-fabsf(x)));
}

__device__ __forceinline__ void gload16(const void* g, void* l) {
    __builtin_amdgcn_global_load_lds(
        (const __attribute__((address_space(1))) void*)g,
        (__attribute__((address_space(3))) void*)l, 16, 0, 0);
}

// ---------------- fp32 -> bf16 weight conversion ----------------
__global__ __launch_bounds__(256) void cvt_kernel(const float* __restrict__ s,
                                                  unsigned short* __restrict__ d, int n) {
    int i = (blockIdx.x * blockDim.x + threadIdx.x) * 4;
    if (i < n) {
        float4 v = *(const float4*)(s + i);
        ushort4v o = {f2bf(v.x), f2bf(v.y), f2bf(v.z), f2bf(v.w)};
        *(ushort4v*)(d + i) = o;
    }
}

// ---------------- fp32 -> fp8 e4m3 (scaled) conversion ----------------
__global__ __launch_bounds__(256) void cvt8_kernel(const float* __restrict__ s,
                                                   unsigned char* __restrict__ d,
                                                   float scale) {
    int i = (blockIdx.x * blockDim.x + threadIdx.x) * 8;
    float4 v0 = *(const float4*)(s + i);
    float4 v1 = *(const float4*)(s + i + 4);
    int lo = __builtin_amdgcn_cvt_pk_fp8_f32(v0.x * scale, v0.y * scale, 0, false);
    lo = __builtin_amdgcn_cvt_pk_fp8_f32(v0.z * scale, v0.w * scale, lo, true);
    int hi = __builtin_amdgcn_cvt_pk_fp8_f32(v1.x * scale, v1.y * scale, 0, false);
    hi = __builtin_amdgcn_cvt_pk_fp8_f32(v1.z * scale, v1.w * scale, hi, true);
    int2 o = {lo, hi};
    *(int2*)(d + i) = o;
}

// ---------------- LayerNorm: fp32 in -> bf16 out ----------------
__global__ __launch_bounds__(256) void ln_kernel(const float* __restrict__ x,
                                                 const float* __restrict__ g,
                                                 const float* __restrict__ b,
                                                 unsigned short* __restrict__ out) {
    const int row = blockIdx.x;
    const float* xr = x + (long)row * DMODEL;
    const int base = threadIdx.x * 8;
    float4 v0 = *(const float4*)(xr + base);
    float4 v1 = *(const float4*)(xr + base + 4);
    float vv[8] = {v0.x, v0.y, v0.z, v0.w, v1.x, v1.y, v1.z, v1.w};
    float s = 0.f, s2 = 0.f;
#pragma unroll
    for (int j = 0; j < 8; j++) { s += vv[j]; s2 += vv[j] * vv[j]; }
#pragma unroll
    for (int off = 32; off >= 1; off >>= 1) {
        s += __shfl_xor(s, off);
        s2 += __shfl_xor(s2, off);
    }
    __shared__ float red[8];
    int wave = threadIdx.x >> 6, lane = threadIdx.x & 63;
    if (lane == 0) { red[wave] = s; red[4 + wave] = s2; }
    __syncthreads();
    s = red[0] + red[1] + red[2] + red[3];
    s2 = red[4] + red[5] + red[6] + red[7];
    float mu = s * (1.f / DMODEL);
    float var = s2 * (1.f / DMODEL) - mu * mu;
    float rs = rsqrtf(var + 1e-5f);
    ushort8v ov;
#pragma unroll
    for (int j = 0; j < 8; j++)
        ov[j] = f2bf((vv[j] - mu) * rs * g[base + j] + b[base + j]);
    *(ushort8v*)&out[(long)row * DMODEL + base] = ov;
}

// ============ 128x256 bf16 MFMA GEMM, 3-buffer LDS, 1 barrier + 1 vmcnt per K-tile ============
// (R7 structure, best measured.) 512 thr (8 waves: wm=w>>2 over M, wn=w&3 over N), BK=64.
// T2 swizzle: stored 16B chunk = logical ^ (row&7), both sides (0 conflicts, verified).
// EPI: 0 = bf16 store (W_in); 3 = fp32 + residual (W_out); 4 = bcp K-split partial (W_xp).

#define BARR __builtin_amdgcn_s_barrier()
#define SCHB __builtin_amdgcn_sched_barrier(0)
#define PRIO1 __builtin_amdgcn_s_setprio(1)
#define PRIO0 __builtin_amdgcn_s_setprio(0)
#define VM6   asm volatile("s_waitcnt vmcnt(6)")
#define LGKM8 do { asm volatile("s_waitcnt lgkmcnt(8)"); SCHB; } while(0)
#define LGKM0 do { asm volatile("s_waitcnt lgkmcnt(0)"); SCHB; } while(0)

#define BUFSZ 49152   // 16KB A + 32KB B

template <int EPI>
__global__ __launch_bounds__(512, 1) void gemm256(const unsigned short* __restrict__ A,
                                                  const unsigned short* __restrict__ B,
                                                  int Kstr, int RY, int KT, int ldc,
                                                  unsigned short* __restrict__ Cbf,
                                                  float* __restrict__ Cf,
                                                  const float* __restrict__ resid,
                                                  float* __restrict__ bcout) {
    __shared__ __align__(16) char lds[3 * BUFSZ];
    const int tid = threadIdx.x;
    const int w = tid >> 6, lane = tid & 63;
    const int wm = w >> 2, wn = w & 3;
    const int lrow = lane & 15;

    const int xcd = blockIdx.x & 7;
    const int l = blockIdx.x >> 3;
    const int by = xcd * RY + (l % RY);
    const int rest = l / RY;
    int bx = 0, kpart = 0;
    if constexpr (EPI == 4) { kpart = rest; } else { bx = rest; }
    const long rowBase = (long)by * 128;
    const long colBase = (long)bx * 256;
    const long K0b = (long)kpart * KT * 128;   // byte offset into K

    const int cb0 = (((lane >> 4))     ^ (lane & 7)) * 16;
    const int cb1 = (((lane >> 4) | 4) ^ (lane & 7)) * 16;
    const char* rdA = lds + (wm * 64 + lrow) * 128;
    const char* rdB = lds + 16384 + (wn * 64 + lrow) * 128;

    const int rsub = lane >> 3;
    const int csrc = (lane & 7) ^ (lane >> 3);
    char* ldsw = lds + w * 1024;
    const size_t Kb = (size_t)Kstr;
    const char* pA[2];
#pragma unroll
    for (int u = 0; u < 2; u++)
        pA[u] = (const char*)(A + (rowBase + u * 64 + w * 8 + rsub) * Kb) + csrc * 16 + K0b;
    const char* pB[4];
#pragma unroll
    for (int u = 0; u < 4; u++)
        pB[u] = (const char*)(B + (colBase + u * 64 + w * 8 + rsub) * Kb) + csrc * 16 + K0b;

    floatx4 acc[4][4];
#pragma unroll
    for (int m = 0; m < 4; m++)
#pragma unroll
        for (int n = 0; n < 4; n++) acc[m][n] = floatx4{0.f, 0.f, 0.f, 0.f};
    bf16x8 af0[4], af1[4], bf0[4], bf1[4];

#define STAGE(BUF, OFF) do { \
    _Pragma("unroll") for (int u_ = 0; u_ < 2; u_++) \
        gload16(pA[u_] + (OFF), ldsw + (BUF)*BUFSZ + u_*8192); \
    _Pragma("unroll") for (int u_ = 0; u_ < 4; u_++) \
        gload16(pB[u_] + (OFF), ldsw + (BUF)*BUFSZ + 16384 + u_*8192); } while(0)

#define MFMA16(AF, BF) do { _Pragma("unroll") \
  for (int m_ = 0; m_ < 4; m_++) { _Pragma("unroll") \
    for (int n_ = 0; n_ < 4; n_++) \
      acc[m_][n_] = __builtin_amdgcn_mfma_f32_16x16x32_bf16(BF[n_], AF[m_], acc[m_][n_], 0,0,0); } } while(0)

    STAGE(0, 0);
    STAGE(1, 128);

    for (int t = 0; t < KT; t++) {
        const int buf = t % 3;
        const int bufS = (t + 2) % 3;
        const long bufOff = (long)buf * BUFSZ;
        const size_t off2 = (size_t)((t + 2 < KT) ? (t + 2) : (KT - 1)) * 128;
        VM6;
        BARR;
        STAGE(bufS, off2);
#pragma unroll
        for (int m_ = 0; m_ < 4; m_++)
            af0[m_] = *(const bf16x8*)(rdA + bufOff + m_ * 2048 + cb0);
#pragma unroll
        for (int n_ = 0; n_ < 4; n_++)
            bf0[n_] = *(const bf16x8*)(rdB + bufOff + n_ * 2048 + cb0);
#pragma unroll
        for (int m_ = 0; m_ < 4; m_++)
            af1[m_] = *(const bf16x8*)(rdA + bufOff + m_ * 2048 + cb1);
#pragma unroll
        for (int n_ = 0; n_ < 4; n_++)
            bf1[n_] = *(const bf16x8*)(rdB + bufOff + n_ * 2048 + cb1);
        LGKM8;
        PRIO1; MFMA16(af0, bf0); PRIO0;
        LGKM0;
        PRIO1; MFMA16(af1, bf1); PRIO0;
    }
#undef STAGE
#undef MFMA16

    // epilogue (C^T layout: lane&15 = M-row, (lane>>4)*4+reg = N-col)
    const int cg = (lane >> 4) * 4;
    if constexpr (EPI == 0) {
#pragma unroll
        for (int mi = 0; mi < 4; mi++)
#pragma unroll
            for (int n = 0; n < 4; n++) {
                long row = rowBase + wm * 64 + mi * 16 + lrow;
                long col = colBase + wn * 64 + n * 16 + cg;
                ushort4v o = {f2bf(acc[mi][n][0]), f2bf(acc[mi][n][1]),
                              f2bf(acc[mi][n][2]), f2bf(acc[mi][n][3])};
                *(ushort4v*)&Cbf[row * ldc + col] = o;
            }
    } else if constexpr (EPI == 3) {
#pragma unroll
        for (int mi = 0; mi < 4; mi++)
#pragma unroll
            for (int n = 0; n < 4; n++) {
                long row = rowBase + wm * 64 + mi * 16 + lrow;
                long col = colBase + wn * 64 + n * 16 + cg;
                floatx4 rv = *(const floatx4*)&resid[row * ldc + col];
                *(floatx4*)&Cf[row * ldc + col] = acc[mi][n] + rv;
            }
    } else {   // EPI == 4: W_xp K-split partial -> bcp[kpart][row][256]
        float* op = bcout + (long)kpart * NTOK * 256;
#pragma unroll
        for (int mi = 0; mi < 4; mi++)
#pragma unroll
            for (int n = 0; n < 4; n++) {
                long row = rowBase + wm * 64 + mi * 16 + lrow;
                long col = wn * 64 + n * 16 + cg;
                *(floatx4*)&op[row * 256 + col] = acc[mi][n];
            }
    }
}

// ============ fp8 W_dt GEMM: same 3-buffer schedule, BK=128 bytes, K=4096 ============
// A8 = xc*4 (e4m3), B8 = W_dt*64 (e4m3); acc*1/256 in epilogue. Grid 512 (32by x 16bx).
// 4 ksteps of mfma_f32_16x16x32_fp8_fp8 per K-tile; frags are 8B (b64 reads, 2-way ok).
__global__ __launch_bounds__(512, 1) void gemm_dt8(const unsigned char* __restrict__ A8,
                                                   const unsigned char* __restrict__ B8,
                                                   const float* __restrict__ bias,
                                                   float* __restrict__ dmean) {
    __shared__ __align__(16) char lds[3 * BUFSZ];
    const int tid = threadIdx.x;
    const int w = tid >> 6, lane = tid & 63;
    const int wm = w >> 2, wn = w & 3;
    const int lrow = lane & 15;

    const int xcd = blockIdx.x & 7;
    const int l = blockIdx.x >> 3;
    const int by = xcd * 4 + (l & 3);
    const int bx = l >> 2;                 // 0..15
    const long rowBase = (long)by * 128;
    const long colBase = (long)bx * 256;

    // frag-read constants: kstep s needs bytes [s*32 + (lane>>4)*8, +8)
    // chunk c = 2s + (lane>>5); inner = ((lane>>4)&1)*8; stored slot = c ^ (row&7)
    int cbs[4];
#pragma unroll
    for (int s = 0; s < 4; s++)
        cbs[s] = (((2 * s + (lane >> 5)) ^ (lane & 7)) * 16) + ((lane >> 4) & 1) * 8;
    const char* rdA = lds + (wm * 64 + lrow) * 128;
    const char* rdB = lds + 16384 + (wn * 64 + lrow) * 128;

    const int rsub = lane >> 3;
    const int csrc = (lane & 7) ^ (lane >> 3);
    char* ldsw = lds + w * 1024;
    const char* pA[2];
#pragma unroll
    for (int u = 0; u < 2; u++)
        pA[u] = (const char*)(A8 + (rowBase + u * 64 + w * 8 + rsub) * (size_t)DINNER) + csrc * 16;
    const char* pB[4];
#pragma unroll
    for (int u = 0; u < 4; u++)
        pB[u] = (const char*)(B8 + (colBase + u * 64 + w * 8 + rsub) * (size_t)DINNER) + csrc * 16;

    floatx4 acc[4][4];
#pragma unroll
    for (int m = 0; m < 4; m++)
#pragma unroll
        for (int n = 0; n < 4; n++) acc[m][n] = floatx4{0.f, 0.f, 0.f, 0.f};
    long a0[4], a1[4], b0[4], b1[4];

#define STAGE8(BUF, OFF) do { \
    _Pragma("unroll") for (int u_ = 0; u_ < 2; u_++) \
        gload16(pA[u_] + (OFF), ldsw + (BUF)*BUFSZ + u_*8192); \
    _Pragma("unroll") for (int u_ = 0; u_ < 4; u_++) \
        gload16(pB[u_] + (OFF), ldsw + (BUF)*BUFSZ + 16384 + u_*8192); } while(0)

#define RD8(AF, BF, BO, CB) do { _Pragma("unroll") \
  for (int m_ = 0; m_ < 4; m_++) AF[m_] = *(const long*)(rdA + (BO) + m_ * 2048 + (CB)); \
  _Pragma("unroll") \
  for (int n_ = 0; n_ < 4; n_++) BF[n_] = *(const long*)(rdB + (BO) + n_ * 2048 + (CB)); } while(0)

#define MM8(AF, BF) do { _Pragma("unroll") \
  for (int m_ = 0; m_ < 4; m_++) { _Pragma("unroll") \
    for (int n_ = 0; n_ < 4; n_++) \
      acc[m_][n_] = __builtin_amdgcn_mfma_f32_16x16x32_fp8_fp8(BF[n_], AF[m_], acc[m_][n_], 0,0,0); } } while(0)

    STAGE8(0, 0);
    STAGE8(1, 128);

    const int KT = DINNER / 128;   // 32 tiles
    for (int t = 0; t < KT; t++) {
        const int buf = t % 3;
        const int bufS = (t + 2) % 3;
        const long bufOff = (long)buf * BUFSZ;
        const size_t off2 = (size_t)((t + 2 < KT) ? (t + 2) : (KT - 1)) * 128;
        VM6;
        BARR;
        STAGE8(bufS, off2);
        RD8(a0, b0, bufOff, cbs[0]);
        RD8(a1, b1, bufOff, cbs[1]);
        LGKM8;
        PRIO1; MM8(a0, b0); PRIO0;
        LGKM0;
        PRIO1; MM8(a1, b1); PRIO0;
        RD8(a0, b0, bufOff, cbs[2]);
        RD8(a1, b1, bufOff, cbs[3]);
        LGKM8;
        PRIO1; MM8(a0, b0); PRIO0;
        LGKM0;
        PRIO1; MM8(a1, b1); PRIO0;
    }
#undef STAGE8
#undef RD8
#undef MM8

    // epilogue: softplus(acc/256 + b_dt) summed over cols -> dmean atomics
    const int cg = (lane >> 4) * 4;
    const float SC = 1.f / 256.f;
    float4 bi[4];
#pragma unroll
    for (int n = 0; n < 4; n++)
        bi[n] = *(const float4*)&bias[colBase + wn * 64 + n * 16 + cg];
#pragma unroll
    for (int mi = 0; mi < 4; mi++) {
        float s = 0.f;
#pragma unroll
        for (int n = 0; n < 4; n++) {
            s += softplusf(acc[mi][n][0] * SC + bi[n].x);
            s += softplusf(acc[mi][n][1] * SC + bi[n].y);
            s += softplusf(acc[mi][n][2] * SC + bi[n].z);
            s += softplusf(acc[mi][n][3] * SC + bi[n].w);
        }
        s += __shfl_xor(s, 16);
        s += __shfl_xor(s, 32);
        if ((lane >> 4) == 0)
            atomicAdd(&dmean[rowBase + wm * 64 + mi * 16 + lrow], s);
    }
}

// ---------------- causal depthwise conv1d + bias + silu (bf16 + scaled fp8 out) ----------------
__global__ __launch_bounds__(256) void conv_silu_kernel(const unsigned short* __restrict__ xr,
                                                        const float* __restrict__ w,
                                                        const float* __restrict__ cb,
                                                        unsigned short* __restrict__ xc,
                                                        unsigned char* __restrict__ xc8) {
    int idx = blockIdx.x * blockDim.x + threadIdx.x;   // NTOK * 512
    int d0 = (idx & 511) * 8;
    int bt = idx >> 9;
    int t = bt & (TT - 1);
    float acc[8];
#pragma unroll
    for (int j = 0; j < 8; j++) acc[j] = cb[d0 + j];
#pragma unroll
    for (int k = 0; k < DCONV; k++) {
        int ts = t - (DCONV - 1) + k;
        if (ts < 0) continue;
        ushort8v v = *(const ushort8v*)&xr[(long)(bt - (DCONV - 1) + k) * (2 * DINNER) + d0];
#pragma unroll
        for (int j = 0; j < 8; j++) acc[j] += bf2f(v[j]) * w[(d0 + j) * DCONV + k];
    }
    float sv[8];
    ushort8v ov;
#pragma unroll
    for (int j = 0; j < 8; j++) { sv[j] = siluf(acc[j]); ov[j] = f2bf(sv[j]); }
    *(ushort8v*)&xc[(long)bt * DINNER + d0] = ov;
    int lo = __builtin_amdgcn_cvt_pk_fp8_f32(sv[0] * 4.f, sv[1] * 4.f, 0, false);
    lo = __builtin_amdgcn_cvt_pk_fp8_f32(sv[2] * 4.f, sv[3] * 4.f, lo, true);
    int hi = __builtin_amdgcn_cvt_pk_fp8_f32(sv[4] * 4.f, sv[5] * 4.f, 0, false);
    hi = __builtin_amdgcn_cvt_pk_fp8_f32(sv[6] * 4.f, sv[7] * 4.f, hi, true);
    int2 o8 = {lo, hi};
    *(int2*)&xc8[(long)bt * DINNER + d0] = o8;
}

// ---------------- bc = sum of 4 K-split partials ----------------
__global__ __launch_bounds__(256) void bcsum_kernel(const float* __restrict__ bcp,
                                                    float* __restrict__ bc) {
    long i = (long)(blockIdx.x * blockDim.x + threadIdx.x) * 4;
    const long S = (long)NTOK * 256;
    float4 a = *(const float4*)(bcp + i);
    float4 b = *(const float4*)(bcp + S + i);
    float4 c = *(const float4*)(bcp + 2*S + i);
    float4 d = *(const float4*)(bcp + 3*S + i);
    float4 o = {a.x+b.x+c.x+d.x, a.y+b.y+c.y+d.y, a.z+b.z+c.z+d.z, a.w+b.w+c.w+d.w};
    *(float4*)(bc + i) = o;
}

// ---------------- sequential selective-scan (1 wave per batch) ----------------
__global__ void scan_kernel(const float* __restrict__ dmean, const float* __restrict__ bcmat,
                            const float* __restrict__ A_log, float* __restrict__ ys) {
    int b = blockIdx.x, lane = threadIdx.x;   // 64 lanes, 2 states each
    float A0 = -expf(A_log[lane]);
    float A1 = -expf(A_log[lane + 64]);
    float h0 = 0.f, h1 = 0.f;
    const float inv = 1.f / (float)DINNER;
    const float* rowp = bcmat + (long)b * TT * (2 * DSTATE);
    const float* dmp = dmean + b * TT;
    float B0 = rowp[lane], B1 = rowp[64 + lane];
    float C0 = rowp[128 + lane], C1 = rowp[192 + lane];
    float DM = dmp[0];
    for (int t = 0; t < TT; t++) {
        float nB0 = 0.f, nB1 = 0.f, nC0 = 0.f, nC1 = 0.f, nDM = 0.f;
        if (t + 1 < TT) {
            const float* nx = rowp + (long)(t + 1) * 256;
            nB0 = nx[lane]; nB1 = nx[64 + lane];
            nC0 = nx[128 + lane]; nC1 = nx[192 + lane];
            nDM = dmp[t + 1];
        }
        float dm = DM * inv;
        h0 = h0 * __expf(dm * A0) + B0;
        h1 = h1 * __expf(dm * A1) + B1;
        float v = h0 * C0 + h1 * C1;
#pragma unroll
        for (int off = 32; off >= 1; off >>= 1) v += __shfl_xor(v, off);
        if (lane == 0) ys[b * TT + t] = v;
        B0 = nB0; B1 = nB1; C0 = nC0; C1 = nC1; DM = nDM;
    }
}

// ---------------- y = (ys + D_skip*xc) * silu(res) ----------------
__global__ __launch_bounds__(256) void ycomb_kernel(const float* __restrict__ ys,
                                                    const unsigned short* __restrict__ xc,
                                                    const unsigned short* __restrict__ xr,
                                                    const float* __restrict__ dskip,
                                                    unsigned short* __restrict__ yc) {
    int idx = blockIdx.x * blockDim.x + threadIdx.x;
    int d0 = (idx & 511) * 8;
    int bt = idx >> 9;
    float y = ys[bt];
    ushort8v xcv = *(const ushort8v*)&xc[(long)bt * DINNER + d0];
    ushort8v rv = *(const ushort8v*)&xr[(long)bt * (2 * DINNER) + DINNER + d0];
    ushort8v ov;
#pragma unroll
    for (int j = 0; j < 8; j++) {
        float val = (y + dskip[d0 + j] * bf2f(xcv[j])) * siluf(bf2f(rv[j]));
        ov[j] = f2bf(val);
    }
    *(ushort8v*)&yc[(long)bt * DINNER + d0] = ov;
}

extern "C" void kernel_launch(void* const* d_in, const int* in_sizes, int n_in,
                              void* d_out, int out_size, void* d_ws, size_t ws_size,
                              hipStream_t stream) {
    const float* x      = (const float*)d_in[0];
    const float* ln_g   = (const float*)d_in[1];
    const float* ln_b   = (const float*)d_in[2];
    const float* W_in   = (const float*)d_in[3];
    const float* conv_w = (const float*)d_in[4];
    const float* conv_b = (const float*)d_in[5];
    const float* W_xp   = (const float*)d_in[6];
    const float* W_dt   = (const float*)d_in[7];
    const float* b_dt   = (const float*)d_in[8];
    const float* A_log  = (const float*)d_in[9];
    const float* D_skip = (const float*)d_in[10];
    const float* W_out  = (const float*)d_in[11];
    float* out = (float*)d_out;

    // workspace carve
    char* ws = (char*)d_ws;
    const size_t nWin  = (size_t)2 * DINNER * DMODEL;
    const size_t nWdt  = (size_t)DINNER * DINNER;
    const size_t nWxp  = (size_t)2 * DSTATE * DINNER;
    const size_t nWout = (size_t)DMODEL * DINNER;

    unsigned short* wb_in  = (unsigned short*)ws; ws += nWin * 2;
    unsigned char*  wb_dt8 = (unsigned char*)ws;  ws += nWdt;
    unsigned short* wb_xp  = (unsigned short*)ws; ws += nWxp * 2;
    unsigned short* wb_out = (unsigned short*)ws; ws += nWout * 2;
    unsigned short* xn = (unsigned short*)ws; ws += (size_t)NTOK * DMODEL * 2;
    unsigned short* xr = (unsigned short*)ws; ws += (size_t)NTOK * 2 * DINNER * 2;
    unsigned short* xc = (unsigned short*)ws; ws += (size_t)NTOK * DINNER * 2;
    unsigned char*  xc8 = (unsigned char*)ws; ws += (size_t)NTOK * DINNER;
    unsigned short* yc = (unsigned short*)ws; ws += (size_t)NTOK * DINNER * 2;
    float* bc    = (float*)ws; ws += (size_t)NTOK * 2 * DSTATE * 4;
    float* bcp   = (float*)ws; ws += (size_t)4 * NTOK * 2 * DSTATE * 4;
    float* dmean = (float*)ws; ws += (size_t)NTOK * 4;
    float* ysb   = (float*)ws; ws += (size_t)NTOK * 4;
    float* h0    = (float*)ws; ws += (size_t)NTOK * DMODEL * 4;
    float* h1    = (float*)ws; ws += (size_t)NTOK * DMODEL * 4;

    const float* hin = x;
    for (int lay = 0; lay < NLAYERS; lay++) {
        float* hout = (lay == NLAYERS - 1) ? out : ((lay & 1) ? h1 : h0);

        cvt_kernel<<<(int)(nWin / 1024), 256, 0, stream>>>(W_in + (size_t)lay * nWin, wb_in, (int)nWin);
        cvt8_kernel<<<(int)(nWdt / 2048), 256, 0, stream>>>(W_dt + (size_t)lay * nWdt, wb_dt8, 64.f);
        cvt_kernel<<<(int)(nWxp / 1024), 256, 0, stream>>>(W_xp + (size_t)lay * nWxp, wb_xp, (int)nWxp);
        cvt_kernel<<<(int)(nWout / 1024), 256, 0, stream>>>(W_out + (size_t)lay * nWout, wb_out, (int)nWout);

        hipMemsetAsync(dmean, 0, (size_t)NTOK * 4, stream);

        // 1) LayerNorm
        ln_kernel<<<NTOK, 256, 0, stream>>>(hin, ln_g + lay * DMODEL, ln_b + lay * DMODEL, xn);

        // 2) x_and_res = xn @ W_in^T  [4096 x 8192], K=2048: grid 32y x 32x = 1024
        gemm256<0><<<1024, 512, 0, stream>>>(
            xn, wb_in, DMODEL, 4, 32, 2 * DINNER, xr, nullptr, nullptr, nullptr);

        // 3) causal depthwise conv + silu (bf16 + fp8 outputs)
        conv_silu_kernel<<<NTOK * 512 / 256, 256, 0, stream>>>(
            xr, conv_w + (size_t)lay * DINNER * DCONV, conv_b + (size_t)lay * DINNER, xc, xc8);

        // 4a) W_dt fp8 GEMM [4096 x 4096], K=4096: grid 32y x 16x = 512
        gemm_dt8<<<512, 512, 0, stream>>>(xc8, wb_dt8, b_dt + (size_t)lay * DINNER, dmean);

        // 4b) W_xp bf16 GEMM [4096 x 256], K-split x4 (KT=16): grid 32y x 4k = 128
        gemm256<4><<<128, 512, 0, stream>>>(
            xc, wb_xp, DINNER, 4, 16, 0, nullptr, nullptr, nullptr, bcp);

        // 4c) bc = sum of partials
        bcsum_kernel<<<(NTOK * 256 / 4) / 256, 256, 0, stream>>>(bcp, bc);

        // 5) sequential scan -> ys
        scan_kernel<<<BB, 64, 0, stream>>>(dmean, bc, A_log + (size_t)lay * DSTATE, ysb);

        // 6) y = (ys + D_skip*xc) * silu(res)
        ycomb_kernel<<<NTOK * 512 / 256, 256, 0, stream>>>(
            ysb, xc, xr, D_skip + (size_t)lay * DINNER, yc);

        // 7) out = yc @ W_out^T + hin  [4096 x 2048], K=4096: grid 32y x 8x = 256
        gemm256<3><<<256, 512, 0, stream>>>(
            yc, wb_out, DINNER, 4, 64, DMODEL, nullptr, hout, hin, nullptr);

        hin = hout;
    }
    (void)in_sizes; (void)n_in; (void)out_size; (void)ws_size;
}